// Round 10
// baseline (1000.660 us; speedup 1.0000x reference)
//
#include <hip/hip_runtime.h>
#include <math.h>

#define L 4096
#define D 1024
#define H 16
#define KV 4
#define DH 64
// G = H/KV = 4

typedef __attribute__((ext_vector_type(8))) short bf16x8;
typedef __attribute__((ext_vector_type(4))) float f32x4;
typedef __attribute__((ext_vector_type(16))) float f32x16;
typedef __attribute__((ext_vector_type(2))) unsigned int u32x2;

static __device__ __forceinline__ unsigned short f2bf(float f) {
    unsigned u = __float_as_uint(f);
    u = (u + 0x7FFF + ((u >> 16) & 1)) >> 16;   // RNE
    return (unsigned short)u;
}

static __device__ __forceinline__ bf16x8 mk8(unsigned a, unsigned b, unsigned c, unsigned d) {
    union { unsigned u[4]; bf16x8 v; } x;
    x.u[0] = a; x.u[1] = b; x.u[2] = c; x.u[3] = d;
    return x.v;
}

#define EXP2F(x) __builtin_amdgcn_exp2f(x)
#define ZERO16 ((f32x16){0.f,0.f,0.f,0.f,0.f,0.f,0.f,0.f,0.f,0.f,0.f,0.f,0.f,0.f,0.f,0.f})

// async global->LDS, 16B per lane; dst must be wave-uniform base (HW: base + lane*16)
#define GLD16(src, dst) \
    __builtin_amdgcn_global_load_lds((__attribute__((address_space(1))) void*)(src), \
                                     (__attribute__((address_space(3))) void*)(dst), 16, 0, 0)

// ---------------------------------------------------------------------------
// prep: x fp32->bf16, and the four weight transposes (dst[n][k] bf16, K=1024).
// ---------------------------------------------------------------------------
__global__ __launch_bounds__(256) void prep_kernel(
        const float* __restrict__ x,  const float* __restrict__ Wq,
        const float* __restrict__ Wk, const float* __restrict__ Wv,
        const float* __restrict__ Wo,
        unsigned short* __restrict__ xb, unsigned short* __restrict__ WqkvT,
        unsigned short* __restrict__ WoT) {
    const int b = blockIdx.x, tid = threadIdx.x;
    if (b < 4096) {
        int i = (b * 256 + tid) * 4;
        float4 v = *(const float4*)&x[i];
        ushort4 o;
        o.x = f2bf(v.x); o.y = f2bf(v.y); o.z = f2bf(v.z); o.w = f2bf(v.w);
        *(ushort4*)&xb[i] = o;
        return;
    }
    __shared__ float t[32][33];
    const float* src; unsigned short* dst; int N, n0, k0;
    if (b < 5120)      { int tq = b - 4096; src = Wq; dst = WqkvT;                     N = 1024; n0 = (tq & 31) * 32; k0 = (tq >> 5) * 32; }
    else if (b < 5376) { int tq = b - 5120; src = Wk; dst = WqkvT + (size_t)1024*1024; N = 256;  n0 = (tq & 7)  * 32; k0 = (tq >> 3) * 32; }
    else if (b < 5632) { int tq = b - 5376; src = Wv; dst = WqkvT + (size_t)1280*1024; N = 256;  n0 = (tq & 7)  * 32; k0 = (tq >> 3) * 32; }
    else               { int tq = b - 5632; src = Wo; dst = WoT;                       N = 1024; n0 = (tq & 31) * 32; k0 = (tq >> 5) * 32; }
    const int tx = tid & 31, ty = tid >> 5;
    #pragma unroll
    for (int j = 0; j < 4; ++j)
        t[ty + 8 * j][tx] = src[(size_t)(k0 + ty + 8 * j) * N + n0 + tx];
    __syncthreads();
    #pragma unroll
    for (int j = 0; j < 4; ++j)
        dst[(size_t)(n0 + ty + 8 * j) * 1024 + k0 + tx] = f2bf(t[tx][ty + 8 * j]);
}

// ---------------------------------------------------------------------------
// bf16 MFMA GEMM (fp32 out) for the Wo projection.
// ---------------------------------------------------------------------------
__global__ __launch_bounds__(256) void gemm_bf16(const unsigned short* __restrict__ A,
                                                 const unsigned short* __restrict__ BT,
                                                 float* __restrict__ C,
                                                 int M, int N, int K) {
    __shared__ unsigned short As[128 * 32];
    __shared__ unsigned short Bs[128 * 32];

    const int tid  = threadIdx.x;
    const int w    = tid >> 6;
    const int lane = tid & 63;
    const int c    = lane & 15;
    const int quad = lane >> 4;
    const int wy = w >> 1, wx = w & 1;
    const int row0 = blockIdx.y * 128;
    const int col0 = blockIdx.x * 128;

    const int ld_row = w * 16 + (lane >> 2);
    const int ld_col = (lane & 3) * 8;

    f32x4 acc[4][4];
    #pragma unroll
    for (int mt = 0; mt < 4; ++mt)
        #pragma unroll
        for (int nt = 0; nt < 4; ++nt)
            acc[mt][nt] = (f32x4){0.f, 0.f, 0.f, 0.f};

    for (int k0 = 0; k0 < K; k0 += 32) {
        __syncthreads();
        GLD16(&A [(size_t)(row0 + ld_row)      * K + k0 + ld_col], &As[w * 512]);
        GLD16(&A [(size_t)(row0 + ld_row + 64) * K + k0 + ld_col], &As[w * 512 + 2048]);
        GLD16(&BT[(size_t)(col0 + ld_row)      * K + k0 + ld_col], &Bs[w * 512]);
        GLD16(&BT[(size_t)(col0 + ld_row + 64) * K + k0 + ld_col], &Bs[w * 512 + 2048]);
        __syncthreads();

        bf16x8 af[4], bfr[4];
        #pragma unroll
        for (int mt = 0; mt < 4; ++mt)
            af[mt] = *(const bf16x8*)&As[(wy * 64 + mt * 16 + c) * 32 + quad * 8];
        #pragma unroll
        for (int nt = 0; nt < 4; ++nt)
            bfr[nt] = *(const bf16x8*)&Bs[(wx * 64 + nt * 16 + c) * 32 + quad * 8];

        #pragma unroll
        for (int mt = 0; mt < 4; ++mt)
            #pragma unroll
            for (int nt = 0; nt < 4; ++nt)
                acc[mt][nt] = __builtin_amdgcn_mfma_f32_16x16x32_bf16(af[mt], bfr[nt], acc[mt][nt], 0, 0, 0);
    }

    #pragma unroll
    for (int mt = 0; mt < 4; ++mt)
        #pragma unroll
        for (int nt = 0; nt < 4; ++nt)
            #pragma unroll
            for (int r = 0; r < 4; ++r)
                C[(size_t)(row0 + wy * 64 + mt * 16 + quad * 4 + r) * N
                  + col0 + wx * 64 + nt * 16 + c] = acc[mt][nt][r];
}

// ---------------------------------------------------------------------------
// Fused QKV GEMM + RoPE epilogue. V is written TRANSPOSED (vbT[kv*DH+d][l])
// so attention can stage V^T rows (L-contiguous) straight into LDS.
// ---------------------------------------------------------------------------
__global__ __launch_bounds__(256) void gemm_qkv_rope(
        const unsigned short* __restrict__ A,
        const unsigned short* __restrict__ BT,
        unsigned short* __restrict__ qb,
        unsigned short* __restrict__ kbuf,
        unsigned short* __restrict__ vbT) {
    __shared__ unsigned short As[128 * 32];
    __shared__ unsigned short Bs[128 * 32];

    const int tid  = threadIdx.x;
    const int w    = tid >> 6;
    const int lane = tid & 63;
    const int c    = lane & 15;
    const int quad = lane >> 4;
    const int wy = w >> 1, wx = w & 1;
    const int row0 = blockIdx.y * 128;
    const int col0 = blockIdx.x * 128;

    const int ld_row = w * 16 + (lane >> 2);
    const int ld_col = (lane & 3) * 8;

    f32x4 acc[4][4];
    #pragma unroll
    for (int mt = 0; mt < 4; ++mt)
        #pragma unroll
        for (int nt = 0; nt < 4; ++nt)
            acc[mt][nt] = (f32x4){0.f, 0.f, 0.f, 0.f};

    for (int k0 = 0; k0 < 1024; k0 += 32) {
        __syncthreads();
        GLD16(&A [(size_t)(row0 + ld_row)      * 1024 + k0 + ld_col], &As[w * 512]);
        GLD16(&A [(size_t)(row0 + ld_row + 64) * 1024 + k0 + ld_col], &As[w * 512 + 2048]);
        GLD16(&BT[(size_t)(col0 + ld_row)      * 1024 + k0 + ld_col], &Bs[w * 512]);
        GLD16(&BT[(size_t)(col0 + ld_row + 64) * 1024 + k0 + ld_col], &Bs[w * 512 + 2048]);
        __syncthreads();

        bf16x8 af[4], bfr[4];
        #pragma unroll
        for (int mt = 0; mt < 4; ++mt)
            af[mt] = *(const bf16x8*)&As[(wy * 64 + mt * 16 + c) * 32 + quad * 8];
        #pragma unroll
        for (int nt = 0; nt < 4; ++nt)
            bfr[nt] = *(const bf16x8*)&Bs[(wx * 64 + nt * 16 + c) * 32 + quad * 8];

        #pragma unroll
        for (int mt = 0; mt < 4; ++mt)
            #pragma unroll
            for (int nt = 0; nt < 4; ++nt)
                acc[mt][nt] = __builtin_amdgcn_mfma_f32_16x16x32_bf16(af[mt], bfr[nt], acc[mt][nt], 0, 0, 0);
    }

    const int colb = col0 + wx * 64;
    if (colb < 1280) {
        unsigned short* dst; int hh, hstride; float scale;
        if (colb < 1024) { dst = qb;   hh = colb >> 6;          hstride = H;  scale = 0.18033688011112042f; }
        else             { dst = kbuf; hh = (colb - 1024) >> 6; hstride = KV; scale = 1.0f; }
        #pragma unroll
        for (int nt = 0; nt < 2; ++nt) {
            int d = nt * 16 + c;
            float invf = EXP2F((float)d * -0.4152410118609203f);
            #pragma unroll
            for (int mt = 0; mt < 4; ++mt)
                #pragma unroll
                for (int r = 0; r < 4; ++r) {
                    int l = row0 + wy * 64 + mt * 16 + quad * 4 + r;
                    float ang = (float)l * invf;
                    float sn = __sinf(ang), cs = __cosf(ang);
                    float x1 = acc[mt][nt][r], x2 = acc[mt][nt + 2][r];
                    dst[((size_t)l * hstride + hh) * DH + d]      = f2bf((x1 * cs - x2 * sn) * scale);
                    dst[((size_t)l * hstride + hh) * DH + d + 32] = f2bf((x2 * cs + x1 * sn) * scale);
                }
        }
    } else {
        // V^T: vbT[(vh*DH + d) * L + l], packed 4 contiguous l per store
        int vh = (colb - 1280) >> 6;
        #pragma unroll
        for (int nt = 0; nt < 4; ++nt)
            #pragma unroll
            for (int mt = 0; mt < 4; ++mt) {
                int l = row0 + wy * 64 + mt * 16 + quad * 4;
                ushort4 o;
                o.x = f2bf(acc[mt][nt][0]); o.y = f2bf(acc[mt][nt][1]);
                o.z = f2bf(acc[mt][nt][2]); o.w = f2bf(acc[mt][nt][3]);
                *(ushort4*)&vbT[(size_t)(vh * DH + nt * 16 + c) * L + l] = o;
            }
    }
}

// ---------------------------------------------------------------------------
// MFMA attention, 32x32x16, 4-WAY KEY SPLIT. Grid (64, KV), 1024 thr =
// 16 waves = 4 heads x 4 key-groups -> 1 block/CU, 4 waves/SIMD.
// Wave w: head kv*4+(w&3), group g=w>>2 owns keys [g*1024,(g+1)*1024),
// 16 iters of 64. Per iter: 16 St + 16 PV MFMA (32x32x16).
//
// REGISTER-BUDGET LAW (R1-R8 empirical): hipcc allocates VGPR budget =
// 256 / min_waves_per_eu, regardless of the max bound:
//   waves_per_eu(2) -> 128 (R1/R3/R4/R6)   waves_per_eu(4 or 4,4) -> 64 (R5/R7/R8)
// flat_work_group_size(1024) independently hard-caps at 128 (16 waves must
// co-reside). waves_per_eu(2) + 1024-thr block => budget 128, demand ~116
// fits, HW residency = 16 waves/CU. R5's slowness re-diagnosed: the 64-reg
// budget squeeze serialized its loop (no spill, but loads at point-of-use);
// the 4-waves/SIMD structure itself is untested at a 128-reg budget.
// (R9 bench was an infra container failure — kernel audited: no OOB, no
// divergent barriers, launchable at 128 regs. Resubmitted unchanged.)
//
// V: staged per-group from vbT (V^T rows) via global_load_lds,
// double-buffered, source pre-swizzled (chunk ^= d&7) -> linear staging
// writes, conflict-reduced PV ds_reads, zero V-transpose VALU.
// Softmax fully in-register (exp2 -> bf16-truncate -> perm pack ->
// permlane32_swap); rowsums = VALU adds on truncated values.
// Epilogue: 4-way combine in 4 quadrant rounds through the dead Vt LDS
// (12 waves x 4 KB = 48 KB per round), then g0 normalizes and stores.
// NOTE (R2): plain loop body only — no [&] lambda (scratch catastrophe).
// ---------------------------------------------------------------------------
__global__ __attribute__((amdgpu_flat_work_group_size(1024, 1024), amdgpu_waves_per_eu(2)))
void attn_mfma_kernel(
        const unsigned short* __restrict__ qb,
        const unsigned short* __restrict__ kb,
        const unsigned short* __restrict__ vbT,
        unsigned short* __restrict__ ob) {
    __shared__ __align__(16) unsigned short Vt[4][2][64][64];  // 64 KB [group][buf][d][key]; epilogue overlay
    __shared__ __align__(16) float Rs[16][2][32];              //  4 KB rowsums [wave][qt][q]

    const int tid  = threadIdx.x;
    const int w    = tid >> 6;        // 0..15
    const int lane = tid & 63;
    const int c32  = lane & 31;
    const int hi   = lane >> 5;
    const int g    = w >> 2;          // key group 0..3
    const int kv = blockIdx.y;
    const int h  = kv * 4 + (w & 3);
    const int q0 = blockIdx.x * 64;
    const int s_base = g * 1024;

    // ---- V staging sources (pre-swizzled): the 4 waves of group g stage
    // the group's [64 d][64 key] tile; wave (w&3) covers rows vrow0..+15
    // via 2 GLD16 slabs of 8 rows. LDS[d][chunk c] holds global chunk
    // c ^ (d&7)  (chunks of 8 keys = 16B).
    const int vrow0 = (w & 3) * 16;
    const int d0 = vrow0 + (lane >> 3);                  // slab 1 adds +8
    const unsigned short* vsrc0 = vbT + (size_t)(kv * DH + d0) * L + s_base
                                  + (((lane & 7) ^ (d0 & 7)) << 3);
    const unsigned short* vsrc1 = vbT + (size_t)(kv * DH + d0 + 8) * L + s_base
                                  + (((lane & 7) ^ ((d0 + 8) & 7)) << 3);

    // Q B-frags: col=q=c32, k-elems d = kd*16 + hi*8 + j
    bf16x8 qf[2][4];
    {
        const unsigned short* qbase = qb + ((size_t)(q0 + c32) * H + h) * DH + hi * 8;
        #pragma unroll
        for (int qt = 0; qt < 2; ++qt)
            #pragma unroll
            for (int kd = 0; kd < 4; ++kd)
                qf[qt][kd] = *(const bf16x8*)&qbase[qt * 32 * H * DH + kd * 16];
    }

    f32x16 oacc[2][2];    // [qt][dt]: col=d=dt*32+c32, row=q=(r&3)+8(r>>2)+4hi
    #pragma unroll
    for (int qt = 0; qt < 2; ++qt)
        #pragma unroll
        for (int dt = 0; dt < 2; ++dt)
            oacc[qt][dt] = ZERO16;
    float rsum[2] = {0.f, 0.f};   // per-lane partial rowsum, q = qt*32 + c32

    const unsigned short* kbase = kb + ((size_t)(s_base + c32) * KV + kv) * DH + hi * 8;

    // ---- prefetch K iter 0; stage V iter 0 into buf 0 ----
    bf16x8 kf[2][4];   // [key-32-tile][kd]: row=key=c32, k-elems d = kd*16+hi*8+j
    #pragma unroll
    for (int a = 0; a < 2; ++a)
        #pragma unroll
        for (int kd = 0; kd < 4; ++kd)
            kf[a][kd] = *(const bf16x8*)&kbase[a * 32 * KV * DH + kd * 16];
    GLD16(vsrc0, &Vt[g][0][vrow0][0]);
    GLD16(vsrc1, &Vt[g][0][vrow0 + 8][0]);

    for (int it = 0; it < 16; ++it) {
        const int buf = it & 1;
        __syncthreads();   // V stage (+K prefetch) drained; prior reads of buf^1 done

        if (it != 15) {    // stage next 64-key tile into the other buffer (async)
            GLD16(vsrc0 + (it + 1) * 64, &Vt[g][buf ^ 1][vrow0][0]);
            GLD16(vsrc1 + (it + 1) * 64, &Vt[g][buf ^ 1][vrow0 + 8][0]);
        }
        const int itn = (it + 1) & 15;

        #pragma unroll
        for (int kt2 = 0; kt2 < 2; ++kt2) {
            bf16x8 pf[2][2];   // [qt][f]: PV A-frags, keys kt2*32 + f*16 + hi*8 + j
            #pragma unroll
            for (int qt = 0; qt < 2; ++qt) {
                // St = K @ Q^T (32x32, K-dim = DH via 4 chained MFMAs)
                f32x16 s = ZERO16;
                #pragma unroll
                for (int kd = 0; kd < 4; ++kd)
                    s = __builtin_amdgcn_mfma_f32_32x32x16_bf16(kf[kt2][kd], qf[qt][kd], s, 0, 0, 0);
                // exp2, truncate to bf16 domain (matches packed PV operand)
                float p[16];
                #pragma unroll
                for (int r = 0; r < 16; ++r)
                    p[r] = __uint_as_float(__float_as_uint(EXP2F(s[r])) & 0xFFFF0000u);
                // rowsum for q = qt*32+c32 over this lane's 16 keys
                float t0 = (p[0] + p[1]) + (p[2] + p[3]);
                float t1 = (p[4] + p[5]) + (p[6] + p[7]);
                float t2 = (p[8] + p[9]) + (p[10] + p[11]);
                float t3 = (p[12] + p[13]) + (p[14] + p[15]);
                rsum[qt] += (t0 + t1) + (t2 + t3);
                // pack key-pairs: u[i] = bf16(p[2i]) | bf16(p[2i+1])<<16
                unsigned u[8];
                #pragma unroll
                for (int i = 0; i < 8; ++i)
                    u[i] = __builtin_amdgcn_perm(__float_as_uint(p[2 * i + 1]),
                                                 __float_as_uint(p[2 * i]), 0x07060302u);
                // cross-half redistribute: swap(u0,u2)->slots{0,2}, swap(u1,u3)->slots{1,3}
                #pragma unroll
                for (int f = 0; f < 2; ++f) {
                    u32x2 e0 = __builtin_amdgcn_permlane32_swap(u[4 * f + 0], u[4 * f + 2], false, false);
                    u32x2 e1 = __builtin_amdgcn_permlane32_swap(u[4 * f + 1], u[4 * f + 3], false, false);
                    pf[qt][f] = mk8(e0.x, e1.x, e0.y, e1.y);
                }
            }
            if (kt2 == 1) {
                // K prefetch next iter (after last St read of kf)
                #pragma unroll
                for (int a = 0; a < 2; ++a)
                    #pragma unroll
                    for (int kd = 0; kd < 4; ++kd)
                        kf[a][kd] = *(const bf16x8*)&kbase[((size_t)itn * 64 + a * 32) * KV * DH + kd * 16];
            }
            // ---- PV: O += P @ V over keys kt2*32..+31 ----
            __builtin_amdgcn_s_setprio(1);
            #pragma unroll
            for (int dt = 0; dt < 2; ++dt)
                #pragma unroll
                for (int f = 0; f < 2; ++f) {
                    // logical chunk = kt2*4 + f*2 + hi, phys = logical ^ (d&7), d = dt*32+c32
                    bf16x8 vf = *(const bf16x8*)&Vt[g][buf][dt * 32 + c32]
                                    [(((kt2 * 4 + f * 2 + hi) ^ (c32 & 7)) << 3)];
                    #pragma unroll
                    for (int qt = 0; qt < 2; ++qt)
                        oacc[qt][dt] = __builtin_amdgcn_mfma_f32_32x32x16_bf16(pf[qt][f], vf, oacc[qt][dt], 0, 0, 0);
                }
            __builtin_amdgcn_s_setprio(0);
        }
    }

    // ---- epilogue: combine hi-halves of rowsums, write Rs ----
    #pragma unroll
    for (int qt = 0; qt < 2; ++qt) {
        u32x2 e = __builtin_amdgcn_permlane32_swap(__float_as_uint(rsum[qt]),
                                                   __float_as_uint(rsum[qt]), false, false);
        float tot = __uint_as_float(e.x) + __uint_as_float(e.y);
        Rs[w][qt][c32] = tot;   // both hi-lanes write identical value (benign)
    }
    __syncthreads();   // all PV reads of Vt complete -> safe to overlay
    // ---- 4-way oacc combine, 4 quadrant rounds through dead Vt (48 KB) ----
    float* Ep = (float*)&Vt[0][0][0][0];
    #pragma unroll
    for (int qt = 0; qt < 2; ++qt)
        #pragma unroll
        for (int dt = 0; dt < 2; ++dt) {
            if (g > 0) {
                float* dst = Ep + (size_t)(w - 4) * 1024 + lane * 16;
                #pragma unroll
                for (int k = 0; k < 4; ++k) {
                    f32x4 val = {oacc[qt][dt][k * 4 + 0], oacc[qt][dt][k * 4 + 1],
                                 oacc[qt][dt][k * 4 + 2], oacc[qt][dt][k * 4 + 3]};
                    *(f32x4*)&dst[k * 4] = val;
                }
            }
            __syncthreads();
            if (g == 0) {
                #pragma unroll
                for (int part = 1; part <= 3; ++part) {
                    const float* src = Ep + (size_t)(part * 4 + w - 4) * 1024 + lane * 16;
                    #pragma unroll
                    for (int k = 0; k < 4; ++k) {
                        f32x4 val = *(const f32x4*)&src[k * 4];
                        oacc[qt][dt][k * 4 + 0] += val[0];
                        oacc[qt][dt][k * 4 + 1] += val[1];
                        oacc[qt][dt][k * 4 + 2] += val[2];
                        oacc[qt][dt][k * 4 + 3] += val[3];
                    }
                }
            }
            __syncthreads();
        }
    if (g == 0) {
        #pragma unroll
        for (int qt = 0; qt < 2; ++qt)
            #pragma unroll
            for (int rr = 0; rr < 4; ++rr) {
                f32x4 r0 = *(const f32x4*)&Rs[w     ][qt][8 * rr + 4 * hi];
                f32x4 r1 = *(const f32x4*)&Rs[w +  4][qt][8 * rr + 4 * hi];
                f32x4 r2 = *(const f32x4*)&Rs[w +  8][qt][8 * rr + 4 * hi];
                f32x4 r3 = *(const f32x4*)&Rs[w + 12][qt][8 * rr + 4 * hi];
                #pragma unroll
                for (int i = 0; i < 4; ++i) {
                    float inv = 1.0f / (r0[i] + r1[i] + r2[i] + r3[i]);
                    int row = q0 + qt * 32 + 8 * rr + 4 * hi + i;
                    #pragma unroll
                    for (int dt = 0; dt < 2; ++dt)
                        ob[(size_t)row * (H * DH) + h * DH + dt * 32 + c32] =
                            f2bf(oacc[qt][dt][rr * 4 + i] * inv);
                }
            }
    }
}

// ---------------------------------------------------------------------------
extern "C" void kernel_launch(void* const* d_in, const int* in_sizes, int n_in,
                              void* d_out, int out_size, void* d_ws, size_t ws_size,
                              hipStream_t stream) {
    const float* x  = (const float*)d_in[0];
    const float* Wq = (const float*)d_in[1];
    const float* Wk = (const float*)d_in[2];
    const float* Wv = (const float*)d_in[3];
    const float* Wo = (const float*)d_in[4];
    float* out = (float*)d_out;

    // ---- workspace (~26.2 MB) ----
    char* ws = (char*)d_ws;
    unsigned short* xb    = (unsigned short*)ws;                      // 8.39 MB
    unsigned short* ob    = xb;                                       // aliases xb (dead after QKV GEMM)
    unsigned short* qb    = (unsigned short*)(ws + 8388608);          // 8.39 MB
    unsigned short* kb    = (unsigned short*)(ws + 16777216);         // 2.10 MB
    unsigned short* vbT   = (unsigned short*)(ws + 18874368);         // 2.10 MB (V transposed [kv*DH+d][L])
    unsigned short* WqkvT = (unsigned short*)(ws + 20971520);         // 3.15 MB
    unsigned short* WoT   = (unsigned short*)(ws + 24117248);         // 2.10 MB

    dim3 blk(256);

    // 1) convert + transpose everything
    prep_kernel<<<6656, blk, 0, stream>>>(x, Wq, Wk, Wv, Wo, xb, WqkvT, WoT);

    // 2) fused QKV projection + RoPE + bf16 pack (V written transposed)
    gemm_qkv_rope<<<dim3(12, 32), blk, 0, stream>>>(xb, WqkvT, qb, kb, vbT);

    // 3) attention: 256 blocks of 16 waves -> 4 waves/SIMD
    attn_mfma_kernel<<<dim3(L / 64, KV), dim3(1024), 0, stream>>>(qb, kb, vbT, ob);

    // 4) output projection
    gemm_bf16<<<dim3(D / 128, L / 128), blk, 0, stream>>>(ob, WoT, out, L, D, D);
}

// Round 11
// 205.523 us; speedup vs baseline: 4.8688x; 4.8688x over previous
//
#include <hip/hip_runtime.h>
#include <math.h>

#define L 4096
#define D 1024
#define H 16
#define KV 4
#define DH 64
// G = H/KV = 4

typedef __attribute__((ext_vector_type(8))) short bf16x8;
typedef __attribute__((ext_vector_type(4))) float f32x4;
typedef __attribute__((ext_vector_type(16))) float f32x16;
typedef __attribute__((ext_vector_type(2))) unsigned int u32x2;

static __device__ __forceinline__ unsigned short f2bf(float f) {
    unsigned u = __float_as_uint(f);
    u = (u + 0x7FFF + ((u >> 16) & 1)) >> 16;   // RNE
    return (unsigned short)u;
}

static __device__ __forceinline__ bf16x8 mk8(unsigned a, unsigned b, unsigned c, unsigned d) {
    union { unsigned u[4]; bf16x8 v; } x;
    x.u[0] = a; x.u[1] = b; x.u[2] = c; x.u[3] = d;
    return x.v;
}

#define EXP2F(x) __builtin_amdgcn_exp2f(x)
#define ZERO16 ((f32x16){0.f,0.f,0.f,0.f,0.f,0.f,0.f,0.f,0.f,0.f,0.f,0.f,0.f,0.f,0.f,0.f})

// async global->LDS, 16B per lane; dst must be wave-uniform base (HW: base + lane*16)
#define GLD16(src, dst) \
    __builtin_amdgcn_global_load_lds((__attribute__((address_space(1))) void*)(src), \
                                     (__attribute__((address_space(3))) void*)(dst), 16, 0, 0)

// ---------------------------------------------------------------------------
// prep: x fp32->bf16, and the four weight transposes (dst[n][k] bf16, K=1024).
// ---------------------------------------------------------------------------
__global__ __launch_bounds__(256) void prep_kernel(
        const float* __restrict__ x,  const float* __restrict__ Wq,
        const float* __restrict__ Wk, const float* __restrict__ Wv,
        const float* __restrict__ Wo,
        unsigned short* __restrict__ xb, unsigned short* __restrict__ WqkvT,
        unsigned short* __restrict__ WoT) {
    const int b = blockIdx.x, tid = threadIdx.x;
    if (b < 4096) {
        int i = (b * 256 + tid) * 4;
        float4 v = *(const float4*)&x[i];
        ushort4 o;
        o.x = f2bf(v.x); o.y = f2bf(v.y); o.z = f2bf(v.z); o.w = f2bf(v.w);
        *(ushort4*)&xb[i] = o;
        return;
    }
    __shared__ float t[32][33];
    const float* src; unsigned short* dst; int N, n0, k0;
    if (b < 5120)      { int tq = b - 4096; src = Wq; dst = WqkvT;                     N = 1024; n0 = (tq & 31) * 32; k0 = (tq >> 5) * 32; }
    else if (b < 5376) { int tq = b - 5120; src = Wk; dst = WqkvT + (size_t)1024*1024; N = 256;  n0 = (tq & 7)  * 32; k0 = (tq >> 3) * 32; }
    else if (b < 5632) { int tq = b - 5376; src = Wv; dst = WqkvT + (size_t)1280*1024; N = 256;  n0 = (tq & 7)  * 32; k0 = (tq >> 3) * 32; }
    else               { int tq = b - 5632; src = Wo; dst = WoT;                       N = 1024; n0 = (tq & 31) * 32; k0 = (tq >> 5) * 32; }
    const int tx = tid & 31, ty = tid >> 5;
    #pragma unroll
    for (int j = 0; j < 4; ++j)
        t[ty + 8 * j][tx] = src[(size_t)(k0 + ty + 8 * j) * N + n0 + tx];
    __syncthreads();
    #pragma unroll
    for (int j = 0; j < 4; ++j)
        dst[(size_t)(n0 + ty + 8 * j) * 1024 + k0 + tx] = f2bf(t[tx][ty + 8 * j]);
}

// ---------------------------------------------------------------------------
// bf16 MFMA GEMM (fp32 out) for the Wo projection. Tile 64x128 (BMxBN),
// 256 thr = 4 waves, wave = 32x64. Grid (N/128, M/64) = 512 blocks = 2/CU
// (R11: the 128x128 tiling gave 256 blocks = 1 block/CU = 1 wave/SIMD —
// latency-naked; halving BM doubles blocks/CU at acc 8xf32x4 = ~80 regs).
// ---------------------------------------------------------------------------
__global__ __launch_bounds__(256) void gemm_bf16(const unsigned short* __restrict__ A,
                                                 const unsigned short* __restrict__ BT,
                                                 float* __restrict__ C,
                                                 int M, int N, int K) {
    __shared__ unsigned short As[64 * 32];
    __shared__ unsigned short Bs[128 * 32];

    const int tid  = threadIdx.x;
    const int w    = tid >> 6;
    const int lane = tid & 63;
    const int c    = lane & 15;
    const int quad = lane >> 4;
    const int wy = w >> 1, wx = w & 1;
    const int row0 = blockIdx.y * 64;
    const int col0 = blockIdx.x * 128;

    const int ld_row = lane >> 2;
    const int ld_col = (lane & 3) * 8;

    f32x4 acc[2][4];
    #pragma unroll
    for (int mt = 0; mt < 2; ++mt)
        #pragma unroll
        for (int nt = 0; nt < 4; ++nt)
            acc[mt][nt] = (f32x4){0.f, 0.f, 0.f, 0.f};

    for (int k0 = 0; k0 < K; k0 += 32) {
        __syncthreads();
        GLD16(&A [(size_t)(row0 + w * 16 + ld_row)      * K + k0 + ld_col], &As[w * 512]);
        GLD16(&BT[(size_t)(col0 + w * 16 + ld_row)      * K + k0 + ld_col], &Bs[w * 512]);
        GLD16(&BT[(size_t)(col0 + w * 16 + 64 + ld_row) * K + k0 + ld_col], &Bs[w * 512 + 2048]);
        __syncthreads();

        bf16x8 af[2], bfr[4];
        #pragma unroll
        for (int mt = 0; mt < 2; ++mt)
            af[mt] = *(const bf16x8*)&As[(wy * 32 + mt * 16 + c) * 32 + quad * 8];
        #pragma unroll
        for (int nt = 0; nt < 4; ++nt)
            bfr[nt] = *(const bf16x8*)&Bs[(wx * 64 + nt * 16 + c) * 32 + quad * 8];

        #pragma unroll
        for (int mt = 0; mt < 2; ++mt)
            #pragma unroll
            for (int nt = 0; nt < 4; ++nt)
                acc[mt][nt] = __builtin_amdgcn_mfma_f32_16x16x32_bf16(af[mt], bfr[nt], acc[mt][nt], 0, 0, 0);
    }

    #pragma unroll
    for (int mt = 0; mt < 2; ++mt)
        #pragma unroll
        for (int nt = 0; nt < 4; ++nt)
            #pragma unroll
            for (int r = 0; r < 4; ++r)
                C[(size_t)(row0 + wy * 32 + mt * 16 + quad * 4 + r) * N
                  + col0 + wx * 64 + nt * 16 + c] = acc[mt][nt][r];
}

// ---------------------------------------------------------------------------
// Fused QKV GEMM + RoPE epilogue. Tile 64x128, grid (12, 64) = 768 blocks
// = 3/CU (was 384 = 1.5/CU with a 2-round tail). V written in plain
// [l][KV][DH] layout (attention reverts to the R3 Vt-staging kernel).
// ---------------------------------------------------------------------------
__global__ __launch_bounds__(256) void gemm_qkv_rope(
        const unsigned short* __restrict__ A,
        const unsigned short* __restrict__ BT,
        unsigned short* __restrict__ qb,
        unsigned short* __restrict__ kbuf,
        unsigned short* __restrict__ vbuf) {
    __shared__ unsigned short As[64 * 32];
    __shared__ unsigned short Bs[128 * 32];

    const int tid  = threadIdx.x;
    const int w    = tid >> 6;
    const int lane = tid & 63;
    const int c    = lane & 15;
    const int quad = lane >> 4;
    const int wy = w >> 1, wx = w & 1;
    const int row0 = blockIdx.y * 64;
    const int col0 = blockIdx.x * 128;

    const int ld_row = lane >> 2;
    const int ld_col = (lane & 3) * 8;

    f32x4 acc[2][4];
    #pragma unroll
    for (int mt = 0; mt < 2; ++mt)
        #pragma unroll
        for (int nt = 0; nt < 4; ++nt)
            acc[mt][nt] = (f32x4){0.f, 0.f, 0.f, 0.f};

    for (int k0 = 0; k0 < 1024; k0 += 32) {
        __syncthreads();
        GLD16(&A [(size_t)(row0 + w * 16 + ld_row)      * 1024 + k0 + ld_col], &As[w * 512]);
        GLD16(&BT[(size_t)(col0 + w * 16 + ld_row)      * 1024 + k0 + ld_col], &Bs[w * 512]);
        GLD16(&BT[(size_t)(col0 + w * 16 + 64 + ld_row) * 1024 + k0 + ld_col], &Bs[w * 512 + 2048]);
        __syncthreads();

        bf16x8 af[2], bfr[4];
        #pragma unroll
        for (int mt = 0; mt < 2; ++mt)
            af[mt] = *(const bf16x8*)&As[(wy * 32 + mt * 16 + c) * 32 + quad * 8];
        #pragma unroll
        for (int nt = 0; nt < 4; ++nt)
            bfr[nt] = *(const bf16x8*)&Bs[(wx * 64 + nt * 16 + c) * 32 + quad * 8];

        #pragma unroll
        for (int mt = 0; mt < 2; ++mt)
            #pragma unroll
            for (int nt = 0; nt < 4; ++nt)
                acc[mt][nt] = __builtin_amdgcn_mfma_f32_16x16x32_bf16(af[mt], bfr[nt], acc[mt][nt], 0, 0, 0);
    }

    const int colb = col0 + wx * 64;
    if (colb < 1280) {
        unsigned short* dst; int hh, hstride; float scale;
        if (colb < 1024) { dst = qb;   hh = colb >> 6;          hstride = H;  scale = 0.18033688011112042f; }
        else             { dst = kbuf; hh = (colb - 1024) >> 6; hstride = KV; scale = 1.0f; }
        #pragma unroll
        for (int nt = 0; nt < 2; ++nt) {
            int d = nt * 16 + c;
            float invf = EXP2F((float)d * -0.4152410118609203f);
            #pragma unroll
            for (int mt = 0; mt < 2; ++mt)
                #pragma unroll
                for (int r = 0; r < 4; ++r) {
                    int l = row0 + wy * 32 + mt * 16 + quad * 4 + r;
                    float ang = (float)l * invf;
                    float sn = __sinf(ang), cs = __cosf(ang);
                    float x1 = acc[mt][nt][r], x2 = acc[mt][nt + 2][r];
                    dst[((size_t)l * hstride + hh) * DH + d]      = f2bf((x1 * cs - x2 * sn) * scale);
                    dst[((size_t)l * hstride + hh) * DH + d + 32] = f2bf((x2 * cs + x1 * sn) * scale);
                }
        }
    } else {
        int vh = (colb - 1280) >> 6;
        #pragma unroll
        for (int mt = 0; mt < 2; ++mt)
            #pragma unroll
            for (int nt = 0; nt < 4; ++nt)
                #pragma unroll
                for (int r = 0; r < 4; ++r) {
                    int l = row0 + wy * 32 + mt * 16 + quad * 4 + r;
                    vbuf[((size_t)l * KV + vh) * DH + nt * 16 + c] = f2bf(acc[mt][nt][r]);
                }
    }
}

// ---------------------------------------------------------------------------
// MFMA attention — VERBATIM the R3 kernel measured at 106.4-106.6 us
// (best attn of the session: VGPR 120, 2 waves/SIMD, plain-loop body).
// R5-R10 established: 1024-thr blocks force a 64-VGPR binary (spill);
// 4-waves/SIMD via thin waves is slower; fat waves spill. This shape is
// the compiler-permitted optimum. Do not touch without new evidence.
// ---------------------------------------------------------------------------
__global__ __attribute__((amdgpu_flat_work_group_size(512, 512), amdgpu_waves_per_eu(2)))
void attn_mfma_kernel(
        const unsigned short* __restrict__ qb,
        const unsigned short* __restrict__ kb,
        const unsigned short* __restrict__ vb,
        unsigned short* __restrict__ ob) {
    __shared__ __align__(16) unsigned short Vt[2][2][64][64];  // 32 KB [group][buf][d][key]
    __shared__ __align__(16) float Ep[4][64][64];              // 64 KB epilogue fp32 partials
    __shared__ __align__(16) float Rs[8][2][32];               //  2 KB rowsums [wave][qt][q]

    const int tid  = threadIdx.x;
    const int w    = tid >> 6;        // 0..7
    const int lane = tid & 63;
    const int c32  = lane & 31;
    const int hi   = lane >> 5;
    const int g    = w >> 2;          // key group
    const int kv = blockIdx.y;
    const int h  = kv * 4 + (w & 3);
    const int q0 = blockIdx.x * 64;
    const int s_base = g * 2048;

    // Q B-frags: col=q=c32, k-elems d = kd*16 + hi*8 + j
    bf16x8 qf[2][4];
    {
        const unsigned short* qbase = qb + ((size_t)(q0 + c32) * H + h) * DH + hi * 8;
        #pragma unroll
        for (int qt = 0; qt < 2; ++qt)
            #pragma unroll
            for (int kd = 0; kd < 4; ++kd)
                qf[qt][kd] = *(const bf16x8*)&qbase[qt * 32 * H * DH + kd * 16];
    }

    f32x16 oacc[2][2];    // [qt][dt]: col=d=c32(+32dt), row=q=(r&3)+8(r>>2)+4hi
    #pragma unroll
    for (int qt = 0; qt < 2; ++qt)
        #pragma unroll
        for (int dt = 0; dt < 2; ++dt)
            oacc[qt][dt] = ZERO16;
    float rsum[2] = {0.f, 0.f};   // per-lane partial rowsum, q = qt*32 + c32

    const int tid8 = tid & 255;                 // id within group
    const int sp = tid8 & 31, dc = tid8 >> 5;   // V staging: keys (2sp,2sp+1), d-chunk dc*8

    const unsigned short* kbase = kb + ((size_t)(s_base + c32) * KV + kv) * DH + hi * 8;
    const unsigned short* vbase = vb + ((size_t)(s_base + 2 * sp) * KV + kv) * DH + dc * 8;
    unsigned short* VtW = &Vt[g][0][0][0];      // wave-group V staging base

    // ---- prefetch iter 0 ----
    int4 vreg0 = *(const int4*)&vbase[0];
    int4 vreg1 = *(const int4*)&vbase[KV * DH];
    bf16x8 kf[2][4];   // [key-32-tile][kd]: row=key=c32, k-elems d = kd*16+hi*8+j
    #pragma unroll
    for (int a = 0; a < 2; ++a)
        #pragma unroll
        for (int kd = 0; kd < 4; ++kd)
            kf[a][kd] = *(const bf16x8*)&kbase[a * 32 * KV * DH + kd * 16];

    for (int it = 0; it < 32; ++it) {
        const int bufo = (it & 1) * (64 * 64);   // LDS double-buffer offset (elems)

        // ---- write Vt[g][buf] (pair-transpose via perm, swizzled) ----
        {
            const unsigned* pa = (const unsigned*)&vreg0;
            const unsigned* pb = (const unsigned*)&vreg1;
            #pragma unroll
            for (int t = 0; t < 4; ++t) {
                unsigned lo = __builtin_amdgcn_perm(pb[t], pa[t], 0x05040100u);
                unsigned hv = __builtin_amdgcn_perm(pb[t], pa[t], 0x07060302u);
                int dl = dc * 8 + 2 * t, dh2 = dl + 1;
                *(unsigned*)&VtW[bufo + dl  * 64 + (((sp >> 2) ^ (dl  & 7)) << 3) + 2 * (sp & 3)] = lo;
                *(unsigned*)&VtW[bufo + dh2 * 64 + (((sp >> 2) ^ (dh2 & 7)) << 3) + 2 * (sp & 3)] = hv;
            }
        }
        __syncthreads();   // Vt[g][buf] visible; prior-iter reads complete

        // ---- V prefetch next (overlaps compute) ----
        const int itn = (it + 1) & 31;
        vreg0 = *(const int4*)&vbase[(size_t)itn * 64 * KV * DH];
        vreg1 = *(const int4*)&vbase[(size_t)itn * 64 * KV * DH + KV * DH];

        #pragma unroll
        for (int kt2 = 0; kt2 < 2; ++kt2) {
            bf16x8 pf[2][2];   // [qt][f]: PV A-frags, keys kt2*32 + f*16 + hi*8 + j
            #pragma unroll
            for (int qt = 0; qt < 2; ++qt) {
                // St = K @ Q^T (32x32, K-dim = DH via 4 chained MFMAs)
                f32x16 s = ZERO16;
                #pragma unroll
                for (int kd = 0; kd < 4; ++kd)
                    s = __builtin_amdgcn_mfma_f32_32x32x16_bf16(kf[kt2][kd], qf[qt][kd], s, 0, 0, 0);
                // exp2, truncate to bf16 domain (matches packed PV operand)
                float p[16];
                #pragma unroll
                for (int r = 0; r < 16; ++r)
                    p[r] = __uint_as_float(__float_as_uint(EXP2F(s[r])) & 0xFFFF0000u);
                // rowsum for q = qt*32+c32 over this lane's 16 keys
                float t0 = (p[0] + p[1]) + (p[2] + p[3]);
                float t1 = (p[4] + p[5]) + (p[6] + p[7]);
                float t2 = (p[8] + p[9]) + (p[10] + p[11]);
                float t3 = (p[12] + p[13]) + (p[14] + p[15]);
                rsum[qt] += (t0 + t1) + (t2 + t3);
                // pack key-pairs: u[i] = bf16(p[2i]) | bf16(p[2i+1])<<16
                unsigned u[8];
                #pragma unroll
                for (int i = 0; i < 8; ++i)
                    u[i] = __builtin_amdgcn_perm(__float_as_uint(p[2 * i + 1]),
                                                 __float_as_uint(p[2 * i]), 0x07060302u);
                // cross-half redistribute: swap(u0,u2)->slots{0,2}, swap(u1,u3)->slots{1,3}
                #pragma unroll
                for (int f = 0; f < 2; ++f) {
                    u32x2 e0 = __builtin_amdgcn_permlane32_swap(u[4 * f + 0], u[4 * f + 2], false, false);
                    u32x2 e1 = __builtin_amdgcn_permlane32_swap(u[4 * f + 1], u[4 * f + 3], false, false);
                    pf[qt][f] = mk8(e0.x, e1.x, e0.y, e1.y);
                }
            }
            if (kt2 == 1) {
                // K prefetch next iter (after last St read of kf)
                #pragma unroll
                for (int a = 0; a < 2; ++a)
                    #pragma unroll
                    for (int kd = 0; kd < 4; ++kd)
                        kf[a][kd] = *(const bf16x8*)&kbase[((size_t)itn * 64 + a * 32) * KV * DH + kd * 16];
            }
            // ---- PV half-tile: O += P @ V over keys kt2*32..+31 ----
            __builtin_amdgcn_s_setprio(1);
            #pragma unroll
            for (int dt = 0; dt < 2; ++dt)
                #pragma unroll
                for (int f = 0; f < 2; ++f) {
                    bf16x8 vf = *(const bf16x8*)&VtW[bufo + (dt * 32 + c32) * 64
                                    + ((((kt2 * 4 + f * 2 + hi) ^ (c32 & 7)) << 3))];
                    #pragma unroll
                    for (int qt = 0; qt < 2; ++qt)
                        oacc[qt][dt] = __builtin_amdgcn_mfma_f32_32x32x16_bf16(pf[qt][f], vf, oacc[qt][dt], 0, 0, 0);
                }
            __builtin_amdgcn_s_setprio(0);
        }
    }

    // ---- epilogue: combine hi-halves of rowsums, then key-halves ----
    #pragma unroll
    for (int qt = 0; qt < 2; ++qt) {
        u32x2 e = __builtin_amdgcn_permlane32_swap(__float_as_uint(rsum[qt]),
                                                   __float_as_uint(rsum[qt]), false, false);
        float tot = __uint_as_float(e.x) + __uint_as_float(e.y);
        Rs[w][qt][c32] = tot;   // both hi-lanes write identical value (benign)
    }
    if (g == 1) {
        #pragma unroll
        for (int qt = 0; qt < 2; ++qt)
            #pragma unroll
            for (int dt = 0; dt < 2; ++dt) {
                const int d = dt * 32 + c32;
                #pragma unroll
                for (int rr = 0; rr < 4; ++rr) {
                    const int gq = (qt * 8 + 2 * rr + hi) ^ (d & 15);   // 16B-granule swizzle
                    f32x4 val = {oacc[qt][dt][rr * 4 + 0], oacc[qt][dt][rr * 4 + 1],
                                 oacc[qt][dt][rr * 4 + 2], oacc[qt][dt][rr * 4 + 3]};
                    *(f32x4*)&Ep[w - 4][d][gq * 4] = val;
                }
            }
    }
    __syncthreads();
    if (g == 0) {
        #pragma unroll
        for (int qt = 0; qt < 2; ++qt)
            #pragma unroll
            for (int dt = 0; dt < 2; ++dt) {
                const int d = dt * 32 + c32;
                #pragma unroll
                for (int rr = 0; rr < 4; ++rr) {
                    const int gq = (qt * 8 + 2 * rr + hi) ^ (d & 15);
                    f32x4 val = *(const f32x4*)&Ep[w][d][gq * 4];
                    oacc[qt][dt][rr * 4 + 0] += val[0];
                    oacc[qt][dt][rr * 4 + 1] += val[1];
                    oacc[qt][dt][rr * 4 + 2] += val[2];
                    oacc[qt][dt][rr * 4 + 3] += val[3];
                }
            }
        #pragma unroll
        for (int qt = 0; qt < 2; ++qt)
            #pragma unroll
            for (int rr = 0; rr < 4; ++rr) {
                f32x4 ra = *(const f32x4*)&Rs[w][qt][8 * rr + 4 * hi];
                f32x4 rb = *(const f32x4*)&Rs[w + 4][qt][8 * rr + 4 * hi];
                #pragma unroll
                for (int i = 0; i < 4; ++i) {
                    float inv = 1.0f / (ra[i] + rb[i]);
                    int row = q0 + qt * 32 + 8 * rr + 4 * hi + i;
                    #pragma unroll
                    for (int dt = 0; dt < 2; ++dt)
                        ob[(size_t)row * (H * DH) + h * DH + dt * 32 + c32] =
                            f2bf(oacc[qt][dt][rr * 4 + i] * inv);
                }
            }
    }
}

// ---------------------------------------------------------------------------
extern "C" void kernel_launch(void* const* d_in, const int* in_sizes, int n_in,
                              void* d_out, int out_size, void* d_ws, size_t ws_size,
                              hipStream_t stream) {
    const float* x  = (const float*)d_in[0];
    const float* Wq = (const float*)d_in[1];
    const float* Wk = (const float*)d_in[2];
    const float* Wv = (const float*)d_in[3];
    const float* Wo = (const float*)d_in[4];
    float* out = (float*)d_out;

    // ---- workspace (~26.2 MB) ----
    char* ws = (char*)d_ws;
    unsigned short* xb    = (unsigned short*)ws;                      // 8.39 MB
    unsigned short* ob    = xb;                                       // aliases xb (dead after QKV GEMM)
    unsigned short* qb    = (unsigned short*)(ws + 8388608);          // 8.39 MB
    unsigned short* kb    = (unsigned short*)(ws + 16777216);         // 2.10 MB
    unsigned short* vb    = (unsigned short*)(ws + 18874368);         // 2.10 MB
    unsigned short* WqkvT = (unsigned short*)(ws + 20971520);         // 3.15 MB
    unsigned short* WoT   = (unsigned short*)(ws + 24117248);         // 2.10 MB

    dim3 blk(256);

    // 1) convert + transpose everything
    prep_kernel<<<6656, blk, 0, stream>>>(x, Wq, Wk, Wv, Wo, xb, WqkvT, WoT);

    // 2) fused QKV projection + RoPE + bf16 pack (64x128 tiles, 768 blocks)
    gemm_qkv_rope<<<dim3(12, 64), blk, 0, stream>>>(xb, WqkvT, qb, kb, vb);

    // 3) attention (R3 kernel, 106.6 us proven)
    attn_mfma_kernel<<<dim3(L / 64, KV), dim3(512), 0, stream>>>(qb, kb, vb, ob);

    // 4) output projection (64x128 tiles, 512 blocks)
    gemm_bf16<<<dim3(D / 128, L / 64), blk, 0, stream>>>(ob, WoT, out, L, D, D);
}